// Round 5
// baseline (196.150 us; speedup 1.0000x reference)
//
#include <hip/hip_runtime.h>

// x[1,32,14,14,14] -> trilinear upsample(224, align_corners) -> 1x1x1 conv
// (32->4) -> softmax(dim=1). Output [1,4,224,224,224] fp32.
//
// Conv commutes with linear interp -> contract 32->4 on the source grid.
// R5: DE-INTERLEAVED STORES. R0-R4 pinned the kernel at ~73 us (2.5 TB/s
// store-side) regardless of compute/occupancy/cache-policy; the remaining
// invariant was each thread storing 4 channel streams 45 MB apart. Softmax
// couples channels at COMPUTE time, but not at STORE time: stage results
// channel-planar in LDS, then store cooperatively -- each wave iteration
// writes 1 KB contiguous in ONE channel (448 float4/ch = 7x64, so waves
// never straddle channels). Fill-like monotone streams per wave.
//
// Block = 8-row band of one d-plane: grid 224*28=6272, 256 threads,
// LDS 31.5 KB -> 5 blocks/CU.
//   P0: x-side d-lerp + 32->4 conv -> e[4][14]  (log2e folded)
//   P1: h-lerp -> g[8][15]
//   P2: w-lerp + softmax -> stg[4][8][56]  (channel-planar)
//   P3: cooperative contiguous per-channel stores

#define NSP 2744             // 14^3
#define NPLANE 196           // 14*14
#define NV  11239424u        // 224^3
#define PLANE_OUT 50176u     // 224*224
#define RATIO (13.0f / 223.0f)
#define LOG2E 1.44269504088896340736f

__global__ __launch_bounds__(256) void fused_decoder(
    const float* __restrict__ x,   // [32][2744]
    const float* __restrict__ W,   // [4][32]
    const float* __restrict__ b,   // [4]
    float* __restrict__ out)       // [4][224][224][224]
{
    __shared__ float4 etab[4][14];     //    896 B: d-lerped conv, 4 src h rows
    __shared__ float4 gtab[8][15];     //  1,920 B: h-lerped lines (pad 14->15)
    __shared__ float4 stg[4][8][56];   // 28,672 B: [c][h_loc][w4] channel-planar

    const int t    = threadIdx.x;
    const int bid  = blockIdx.x;
    const int dd   = bid / 28;          // output d-plane
    const int band = bid - dd * 28;
    const int h0   = band * 8;          // first output h row of this band

    const float posd = (float)dd * RATIO;
    const int   i0d  = min((int)posd, 12);
    const float wd   = posd - (float)i0d;

    const float posh0 = (float)h0 * RATIO;
    const int   hs0   = min((int)posh0, 12);   // first source h row needed

    // ---- P0: d-lerp x, then 32->4 conv, for 4 source h rows x 14 w ----
    if (t < 56) {
        int j  = t / 14;                       // source-row slot 0..3
        int iw = t - j * 14;
        int sr = min(hs0 + j, 13);
        int base0 = (i0d * 14 + sr) * 14 + iw;
        int base1 = base0 + NPLANE;            // next d-plane (i0d<=12 -> ok)
        float a0 = b[0], a1 = b[1], a2 = b[2], a3 = b[3];
#pragma unroll
        for (int c = 0; c < 32; ++c) {
            float x0 = x[c * NSP + base0];
            float x1 = x[c * NSP + base1];
            float xv = fmaf(wd, x1 - x0, x0);  // d-lerp on the input side
            a0 = fmaf(W[c],      xv, a0);
            a1 = fmaf(W[32 + c], xv, a1);
            a2 = fmaf(W[64 + c], xv, a2);
            a3 = fmaf(W[96 + c], xv, a3);
        }
        etab[j][iw] = make_float4(a0 * LOG2E, a1 * LOG2E, a2 * LOG2E, a3 * LOG2E);
    }
    __syncthreads();

    // ---- P1: h-lerp -> gtab[h_loc][iw] ----
    if (t < 112) {
        int hl = t / 14;
        int iw = t - hl * 14;
        int h  = h0 + hl;
        float posh = (float)h * RATIO;
        int   i0h  = min((int)posh, 12);
        float wh   = posh - (float)i0h;
        int   j    = i0h - hs0;                // 0 or 1 (band spans <1 src row)
        float4 e0 = etab[j][iw], e1 = etab[j + 1][iw];
        float4 gv;
        gv.x = fmaf(wh, e1.x - e0.x, e0.x);
        gv.y = fmaf(wh, e1.y - e0.y, e0.y);
        gv.z = fmaf(wh, e1.z - e0.z, e0.z);
        gv.w = fmaf(wh, e1.w - e0.w, e0.w);
        gtab[hl][iw] = gv;
    }
    __syncthreads();

    // ---- P2: w-lerp + softmax -> channel-planar staging ----
    for (int it = t; it < 448; it += 256) {    // 448 = 8 rows * 56 w-groups
        int hl = it / 56;
        int w4 = it - hl * 56;
        int wb = w4 * 4;
        float posw0 = (float)wb * RATIO;
        int   iw0   = min((int)posw0, 12);
        float u     = posw0 - (float)iw0;
        float4 g0 = gtab[hl][iw0];
        float4 g1 = gtab[hl][iw0 + 1];
        float4 g2 = gtab[hl][min(iw0 + 2, 13)];

        float4 d10, d21;
        d10.x = g1.x - g0.x; d10.y = g1.y - g0.y; d10.z = g1.z - g0.z; d10.w = g1.w - g0.w;
        d21.x = g2.x - g1.x; d21.y = g2.y - g1.y; d21.z = g2.z - g1.z; d21.w = g2.w - g1.w;

        float4 res[4];
#pragma unroll
        for (int j = 0; j < 4; ++j) {
            // piecewise-linear in u: val = g0 + min(u,1)*d10 + max(u-1,0)*d21
            float a  = fminf(u, 1.0f);
            float bb = u - a;
            float t0 = fmaf(bb, d21.x, fmaf(a, d10.x, g0.x));
            float t1 = fmaf(bb, d21.y, fmaf(a, d10.y, g0.y));
            float t2 = fmaf(bb, d21.z, fmaf(a, d10.z, g0.z));
            float t3 = fmaf(bb, d21.w, fmaf(a, d10.w, g0.w));
            float m  = fmaxf(fmaxf(t0, t1), fmaxf(t2, t3));
            float e0 = exp2f(t0 - m), e1 = exp2f(t1 - m);
            float e2 = exp2f(t2 - m), e3 = exp2f(t3 - m);
            float s  = (e0 + e1) + (e2 + e3);
            float inv = __builtin_amdgcn_rcpf(s);  // 1-ulp rcp vs 1.9e-2 thresh
            res[j].x = e0 * inv;
            res[j].y = e1 * inv;
            res[j].z = e2 * inv;
            res[j].w = e3 * inv;
            u += RATIO;
        }

        stg[0][hl][w4] = make_float4(res[0].x, res[1].x, res[2].x, res[3].x);
        stg[1][hl][w4] = make_float4(res[0].y, res[1].y, res[2].y, res[3].y);
        stg[2][hl][w4] = make_float4(res[0].z, res[1].z, res[2].z, res[3].z);
        stg[3][hl][w4] = make_float4(res[0].w, res[1].w, res[2].w, res[3].w);
    }
    __syncthreads();

    // ---- P3: cooperative stores; each wave-iter = 1 KB contiguous, 1 channel.
    // 4*448 = 1792 float4 = 7 * 256; 448 = 7*64 -> waves never straddle c. ----
    const float4* s = &stg[0][0][0];
    const unsigned base = (unsigned)dd * PLANE_OUT + (unsigned)h0 * 224u;
#pragma unroll
    for (int k = 0; k < 7; ++k) {
        int idx = k * 256 + t;
        int c   = idx / 448;
        int r   = idx - c * 448;               // float4 index within channel run
        *(float4*)(out + (unsigned)c * NV + base + (unsigned)r * 4u) = s[idx];
    }
}

extern "C" void kernel_launch(void* const* d_in, const int* in_sizes, int n_in,
                              void* d_out, int out_size, void* d_ws, size_t ws_size,
                              hipStream_t stream) {
    const float* x = (const float*)d_in[0];   // [1,32,14,14,14]
    const float* W = (const float*)d_in[1];   // [4,32]
    const float* b = (const float*)d_in[2];   // [4]
    float* out = (float*)d_out;               // [1,4,224,224,224]
    (void)d_ws; (void)ws_size;

    fused_decoder<<<224 * 28, 256, 0, stream>>>(x, W, b, out);
}